// Round 9
// baseline (1654.788 us; speedup 1.0000x reference)
//
#include <hip/hip_runtime.h>

typedef __attribute__((ext_vector_type(8))) short short8v;
typedef __attribute__((ext_vector_type(4))) float f32x4;
typedef __attribute__((ext_vector_type(4))) unsigned int uint4v;

#define GLOBAL_AS(p) ((const __attribute__((address_space(1))) void*)(p))
#define LDS_AS(p)    ((__attribute__((address_space(3))) void*)(p))
#define WAITV(n) asm volatile("s_waitcnt vmcnt(" #n ")" ::: "memory")
#define BARRIER() __builtin_amdgcn_s_barrier()

__device__ __forceinline__ unsigned short f2bf(float f) {
  unsigned int u = __builtin_bit_cast(unsigned int, f);
  u += 0x7fffu + ((u >> 16) & 1u);
  return (unsigned short)(u >> 16);
}
__device__ __forceinline__ float bf2f(unsigned short u) {
  unsigned int x = ((unsigned int)u) << 16;
  return __builtin_bit_cast(float, x);
}

// ---------------------------------------------------------------------------
// Transpose fp32 [K,N] -> bf16 [N,K]
__global__ __launch_bounds__(256) void transpose_to_bf16(
    const float* __restrict__ src, unsigned short* __restrict__ dst,
    int K, int N, int ntx) {
  __shared__ float tile[32][33];
  const int bx = blockIdx.x % ntx;
  const int by = blockIdx.x / ntx;
  const int tx = threadIdx.x & 31, ty = threadIdx.x >> 5;
  const int k0 = by * 32, n0 = bx * 32;
#pragma unroll
  for (int i = 0; i < 32; i += 8)
    tile[ty + i][tx] = src[(size_t)(k0 + ty + i) * N + n0 + tx];
  __syncthreads();
#pragma unroll
  for (int i = 0; i < 32; i += 8)
    dst[(size_t)(n0 + ty + i) * K + k0 + tx] = f2bf(tile[tx][ty + i]);
}

// fp32 -> bf16, 8 elements/thread
__global__ __launch_bounds__(256) void cvt_f32_bf16(
    const float* __restrict__ s, unsigned short* __restrict__ d) {
  size_t i = ((size_t)blockIdx.x * 256 + threadIdx.x) * 8;
  f32x4 v0 = *(const f32x4*)(s + i);
  f32x4 v1 = *(const f32x4*)(s + i + 4);
  union U8 { uint4v v; unsigned short us[8]; } o;
  o.us[0] = f2bf(v0.x); o.us[1] = f2bf(v0.y); o.us[2] = f2bf(v0.z); o.us[3] = f2bf(v0.w);
  o.us[4] = f2bf(v1.x); o.us[5] = f2bf(v1.y); o.us[6] = f2bf(v1.z); o.us[7] = f2bf(v1.w);
  *(uint4v*)(d + i) = o.v;
}

// combined bias concat: b1 = [bd_k|bd_v|bq] (3072), b2 = [bu_k|bu_v] (4096)
__global__ __launch_bounds__(256) void fill_bias(
    const float* __restrict__ bd_k, const float* __restrict__ bd_v,
    const float* __restrict__ bq, const float* __restrict__ bu_k,
    const float* __restrict__ bu_v, float* __restrict__ b1, float* __restrict__ b2) {
  int i = blockIdx.x * 256 + threadIdx.x;
  if (i < 512) b1[i] = bd_k[i];
  else if (i < 1024) b1[i] = bd_v[i - 512];
  else if (i < 3072) b1[i] = bq[i - 1024];
  else if (i < 5120) b2[i - 3072] = bu_k[i - 3072];
  else if (i < 7168) b2[i - 3072] = bu_v[i - 5120];
}

// ---------------------------------------------------------------------------
// 256x128x64 bf16 GEMM block, 4 waves (2Mx2N), per-wave 128x64, 16x16x32 MFMA.
// KEY CHANGE vs R3-R8: B fragments load GLOBAL->REG (weights are L2/LLC-hot);
// LDS holds A only (64KB dbuf) -> per-tile LDS traffic cut ~60% (the measured
// 62%-MfmaUtil ceiling was LDS-BW: 192KB frag reads + 64KB writes vs 620cy
// MFMA). 256-thread blocks -> 2 blocks/CU (two barrier domains hide each
// other's stalls). One barrier/K-tile; counted vmcnt(16) double-buffer.
// Grid bm-fastest so same-bn blocks (shared 1MB B panel) are XCD-contiguous.
template <int OUT_BF16>
__global__ __launch_bounds__(256, 2) void gemm_bt(
    const unsigned short* __restrict__ A, int lda, int nsplit_col, int acol_off,
    const unsigned short* __restrict__ Bt, int ldb,
    const float* __restrict__ bias, void* __restrict__ Cp, int ldc,
    int K, int ntm) {
  __shared__ unsigned short Als[2][256 * 64];  // A dbuf, 64KB
  const int t = threadIdx.x;
  const int lane = t & 63, wave = t >> 6;

  // bijective XCD swizzle (grids here are multiples of 8), bm-fastest
  const int qx = gridDim.x >> 3;
  const int bid = (blockIdx.x & 7) * qx + (blockIdx.x >> 3);
  const int bm = (bid % ntm) * 256;
  const int bn = (bid / ntm) * 128;
  const unsigned short* Ab = A + (bn >= nsplit_col ? acol_off : 0);

  const int wr = wave >> 1, wc = wave & 1;
  const int g = lane >> 4, r = lane & 15;
  const int NT = K >> 6;

  f32x4 acc[8][4];
#pragma unroll
  for (int i = 0; i < 8; ++i)
#pragma unroll
    for (int j = 0; j < 4; ++j) acc[i][j] = (f32x4){0.f, 0.f, 0.f, 0.f};

  // A staging: 8 issues/tile, each 32 rows x 64 cols (256 thr x 16B).
  // thread t -> row t>>3, chunk t&7; source inverse-XOR-swizzled.
  const int srow = t >> 3;
  const int jsrc = (t & 7) ^ (srow & 7);
  const unsigned short* aptr = Ab + (size_t)(bm + srow) * lda + (jsrc << 3);

  auto stage = [&](int kt, int buf) {
    const unsigned short* ak = aptr + (size_t)kt * 64;
    unsigned short* ld = &Als[buf][wave * 512];
#pragma unroll
    for (int u = 0; u < 8; ++u)
      __builtin_amdgcn_global_load_lds(GLOBAL_AS(ak + (size_t)(u * 32) * lda),
                                       LDS_AS(ld + u * 2048), 16, 0, 0);
  };

  // B fragment gather: lane (g,r), frag(ni,ks) = 16B at
  // B^T[bn + wc*64 + ni*16 + r][kt*64 + (ks*4+g)*8]  (bit-identical to LDS path)
  const unsigned short* bptr = Bt + (size_t)(bn + wc * 64 + r) * ldb + (g << 3);
  auto loadB = [&](short8v (&bx)[4][2], int kt) {
    const unsigned short* p = bptr + (size_t)kt * 64;
#pragma unroll
    for (int ni = 0; ni < 4; ++ni)
#pragma unroll
      for (int ks = 0; ks < 2; ++ks)
        bx[ni][ks] = *(const short8v*)(p + (size_t)ni * 16 * ldb + ks * 32);
  };

  auto compute = [&](int buf, short8v (&bx)[4][2]) {
#pragma unroll
    for (int ks = 0; ks < 2; ++ks) {
      const int c16 = (((ks << 2) + g) ^ (r & 7)) << 3;
      __builtin_amdgcn_s_setprio(1);
#pragma unroll
      for (int mi = 0; mi < 8; ++mi) {
        short8v af = *(const short8v*)&Als[buf][(wr * 128 + mi * 16 + r) * 64 + c16];
#pragma unroll
        for (int ni = 0; ni < 4; ++ni)
          acc[mi][ni] = __builtin_amdgcn_mfma_f32_16x16x32_bf16(
              af, bx[ni][ks], acc[mi][ni], 0, 0, 0);
      }
      __builtin_amdgcn_s_setprio(0);
    }
  };

  short8v bA[4][2], bB[4][2];
  // prologue: tile 0 in flight (16 vmem)
  stage(0, 0);
  loadB(bA, 0);

  for (int T = 0; T < NT; T += 2) {
    // ---- even tile T: buf0 + bA; prefetch T+1 -> buf1 + bB
    if (T + 1 < NT) { stage(T + 1, 1); loadB(bB, T + 1); WAITV(16); }
    else { WAITV(0); }
    BARRIER();
    compute(0, bA);
    // ---- odd tile T+1: buf1 + bB; prefetch T+2 -> buf0 + bA
    if (T + 2 < NT) { stage(T + 2, 0); loadB(bA, T + 2); WAITV(16); }
    else { WAITV(0); }
    BARRIER();
    compute(1, bB);
  }

#pragma unroll
  for (int ni = 0; ni < 4; ++ni) {
    const int col = bn + wc * 64 + ni * 16 + r;
    const float bv = bias[col];
#pragma unroll
    for (int mi = 0; mi < 8; ++mi) {
      const int row0 = bm + wr * 128 + mi * 16 + (g << 2);
#pragma unroll
      for (int j = 0; j < 4; ++j) {
        float v = acc[mi][ni][j] + bv;
        if (OUT_BF16)
          ((unsigned short*)Cp)[(size_t)(row0 + j) * ldc + col] = f2bf(v);
        else
          ((float*)Cp)[(size_t)(row0 + j) * ldc + col] = v;
      }
    }
  }
}

// ---------------------------------------------------------------------------
// Per-token head-vs-head attention (16x16 per token), fp32 math.
__global__ __launch_bounds__(256) void attn_kernel(
    const unsigned short* __restrict__ out1, const unsigned short* __restrict__ kv,
    unsigned short* __restrict__ aout) {
  const int s = blockIdx.x;
  const int t = threadIdx.x;
  __shared__ float qs[16 * 132], ks2[16 * 132], vs[16 * 132];
  __shared__ float attn[256];
  const int h = t >> 4, d0 = (t & 15) * 8;

  union U8 { uint4v v; unsigned short us[8]; };
  U8 qv, kv8, vv;
  qv.v = *(const uint4v*)(out1 + (size_t)s * 3072 + 1024 + t * 8);
  kv8.v = *(const uint4v*)(kv + (size_t)s * 4096 + t * 8);
  vv.v = *(const uint4v*)(kv + (size_t)s * 4096 + 2048 + t * 8);
#pragma unroll
  for (int j = 0; j < 8; ++j) {
    qs[h * 132 + d0 + j] = bf2f(qv.us[j]);
    ks2[h * 132 + d0 + j] = bf2f(kv8.us[j]);
    vs[h * 132 + d0 + j] = bf2f(vv.us[j]);
  }
  __syncthreads();

  const int gg0 = t & 15;
  const f32x4* qrow = (const f32x4*)&qs[h * 132];
  const f32x4* krow = (const f32x4*)&ks2[gg0 * 132];
  float acc = 0.f;
#pragma unroll
  for (int dd = 0; dd < 32; ++dd) {
    f32x4 a4 = qrow[dd], b4 = krow[dd];
    acc += a4.x * b4.x + a4.y * b4.y + a4.z * b4.z + a4.w * b4.w;
  }
  acc *= 0.08838834764831845f;
  float mx = acc;
#pragma unroll
  for (int o = 8; o; o >>= 1) mx = fmaxf(mx, __shfl_xor(mx, o));
  float e = __expf(acc - mx);
  float sm = e;
#pragma unroll
  for (int o = 8; o; o >>= 1) sm += __shfl_xor(sm, o);
  attn[t] = e / sm;
  __syncthreads();

  f32x4 o0 = (f32x4){0.f, 0.f, 0.f, 0.f}, o1 = (f32x4){0.f, 0.f, 0.f, 0.f};
#pragma unroll
  for (int gg = 0; gg < 16; ++gg) {
    const float a = attn[(h << 4) + gg];
    f32x4 v0 = *(const f32x4*)&vs[gg * 132 + d0];
    f32x4 v1 = *(const f32x4*)&vs[gg * 132 + d0 + 4];
    o0 += v0 * a;
    o1 += v1 * a;
  }
  U8 ov;
  ov.us[0] = f2bf(o0.x); ov.us[1] = f2bf(o0.y); ov.us[2] = f2bf(o0.z); ov.us[3] = f2bf(o0.w);
  ov.us[4] = f2bf(o1.x); ov.us[5] = f2bf(o1.y); ov.us[6] = f2bf(o1.z); ov.us[7] = f2bf(o1.w);
  *(uint4v*)(aout + (size_t)s * 2048 + t * 8) = ov.v;
}

// ---------------------------------------------------------------------------
extern "C" void kernel_launch(void* const* d_in, const int* in_sizes, int n_in,
                              void* d_out, int out_size, void* d_ws, size_t ws_size,
                              hipStream_t stream) {
  (void)in_sizes; (void)n_in; (void)out_size; (void)ws_size;
  const float* x    = (const float*)d_in[0];
  const float* Wd_k = (const float*)d_in[1];
  const float* bd_k = (const float*)d_in[2];
  const float* Wu_k = (const float*)d_in[3];
  const float* bu_k = (const float*)d_in[4];
  const float* Wd_v = (const float*)d_in[5];
  const float* bd_v = (const float*)d_in[6];
  const float* Wu_v = (const float*)d_in[7];
  const float* bu_v = (const float*)d_in[8];
  const float* Wq   = (const float*)d_in[9];
  const float* bq   = (const float*)d_in[10];
  const float* Wo   = (const float*)d_in[11];
  const float* bo   = (const float*)d_in[12];

  char* ws = (char*)d_ws;
  unsigned short* w1t  = (unsigned short*)(ws);             // [3072][2048] bf16
  unsigned short* w2t  = (unsigned short*)(ws + 12582912);  // [4096][512]  bf16
  unsigned short* w3t  = (unsigned short*)(ws + 16777216);  // [2048][2048] bf16
  float*          b1   = (float*)(ws + 25165824);           // [3072]
  float*          b2   = (float*)(ws + 25178112);           // [4096]
  unsigned short* xb   = (unsigned short*)(ws + 25194496);  // [16384][2048] bf16
  unsigned short* out1 = (unsigned short*)(ws + 92303360);  // [16384][3072] bf16
  unsigned short* kvb  = (unsigned short*)(ws + 192966656); // [16384][4096] bf16
  unsigned short* attO = xb;  // reuse xb after GEMM1

  dim3 blk(256);

  transpose_to_bf16<<<dim3(16 * 64), blk, 0, stream>>>(Wd_k, w1t,               2048, 512, 16);
  transpose_to_bf16<<<dim3(16 * 64), blk, 0, stream>>>(Wd_v, w1t + 512 * 2048,  2048, 512, 16);
  transpose_to_bf16<<<dim3(64 * 64), blk, 0, stream>>>(Wq,   w1t + 1024 * 2048, 2048, 2048, 64);
  transpose_to_bf16<<<dim3(64 * 16), blk, 0, stream>>>(Wu_k, w2t,               512, 2048, 64);
  transpose_to_bf16<<<dim3(64 * 16), blk, 0, stream>>>(Wu_v, w2t + 2048 * 512,  512, 2048, 64);
  transpose_to_bf16<<<dim3(64 * 64), blk, 0, stream>>>(Wo,   w3t,               2048, 2048, 64);

  fill_bias<<<dim3(28), blk, 0, stream>>>(bd_k, bd_v, bq, bu_k, bu_v, b1, b2);

  cvt_f32_bf16<<<dim3(16384), blk, 0, stream>>>(x, xb);

  // GEMM1: [16384,2048]@[2048,3072] -> out1 (cache_k|cache_v|q); 64x24 tiles
  gemm_bt<1><<<dim3(64 * 24), blk, 0, stream>>>(
      xb, 2048, 1 << 30, 0, w1t, 2048, b1, out1, 3072, 2048, 64);

  // GEMM2 fused: k|v = [cache_k|cache_v]@blockdiag(Wu_k,Wu_v) -> kvb; 64x32
  gemm_bt<1><<<dim3(64 * 32), blk, 0, stream>>>(
      out1, 3072, 2048, 512, w2t, 512, b2, kvb, 4096, 512, 64);

  // per-token attention
  attn_kernel<<<dim3(16384), blk, 0, stream>>>(out1, kvb, attO);

  // GEMM3: attO@Wo + bo -> d_out fp32; 64x16
  gemm_bt<0><<<dim3(64 * 16), blk, 0, stream>>>(
      attO, 2048, 1 << 30, 0, w3t, 2048, bo, (float*)d_out, 2048, 2048, 64);
}

// Round 10
// 580.943 us; speedup vs baseline: 2.8485x; 2.8485x over previous
//
#include <hip/hip_runtime.h>

typedef __attribute__((ext_vector_type(8))) short short8v;
typedef __attribute__((ext_vector_type(4))) float f32x4;
typedef __attribute__((ext_vector_type(4))) unsigned int uint4v;

#define GLOBAL_AS(p) ((const __attribute__((address_space(1))) void*)(p))
#define LDS_AS(p)    ((__attribute__((address_space(3))) void*)(p))
#define WAITV(n) asm volatile("s_waitcnt vmcnt(" #n ")" ::: "memory")
#define BARRIER() __builtin_amdgcn_s_barrier()

__device__ __forceinline__ unsigned short f2bf(float f) {
  unsigned int u = __builtin_bit_cast(unsigned int, f);
  u += 0x7fffu + ((u >> 16) & 1u);
  return (unsigned short)(u >> 16);
}
__device__ __forceinline__ float bf2f(unsigned short u) {
  unsigned int x = ((unsigned int)u) << 16;
  return __builtin_bit_cast(float, x);
}

// ---------------------------------------------------------------------------
// Transpose fp32 [K,N] -> bf16 [N,K]
__global__ __launch_bounds__(256) void transpose_to_bf16(
    const float* __restrict__ src, unsigned short* __restrict__ dst,
    int K, int N, int ntx) {
  __shared__ float tile[32][33];
  const int bx = blockIdx.x % ntx;
  const int by = blockIdx.x / ntx;
  const int tx = threadIdx.x & 31, ty = threadIdx.x >> 5;
  const int k0 = by * 32, n0 = bx * 32;
#pragma unroll
  for (int i = 0; i < 32; i += 8)
    tile[ty + i][tx] = src[(size_t)(k0 + ty + i) * N + n0 + tx];
  __syncthreads();
#pragma unroll
  for (int i = 0; i < 32; i += 8)
    dst[(size_t)(n0 + ty + i) * K + k0 + tx] = f2bf(tile[tx][ty + i]);
}

// fp32 -> bf16, 8 elements/thread; block o handles row (o&7)*2048 + (o>>3)
// of the [16384][2048] matrix so xb rows land on the XCD that GEMM1 reads them.
__global__ __launch_bounds__(256) void cvt_f32_bf16(
    const float* __restrict__ s, unsigned short* __restrict__ d) {
  const int o = blockIdx.x;
  const size_t row = (size_t)((o & 7) * 2048 + (o >> 3));
  size_t i = row * 2048 + threadIdx.x * 8;
  f32x4 v0 = *(const f32x4*)(s + i);
  f32x4 v1 = *(const f32x4*)(s + i + 4);
  union U8 { uint4v v; unsigned short us[8]; } o8;
  o8.us[0] = f2bf(v0.x); o8.us[1] = f2bf(v0.y); o8.us[2] = f2bf(v0.z); o8.us[3] = f2bf(v0.w);
  o8.us[4] = f2bf(v1.x); o8.us[5] = f2bf(v1.y); o8.us[6] = f2bf(v1.z); o8.us[7] = f2bf(v1.w);
  *(uint4v*)(d + i) = o8.v;
}

// combined bias concat: b1 = [bd_k|bd_v|bq] (3072), b2 = [bu_k|bu_v] (4096)
__global__ __launch_bounds__(256) void fill_bias(
    const float* __restrict__ bd_k, const float* __restrict__ bd_v,
    const float* __restrict__ bq, const float* __restrict__ bu_k,
    const float* __restrict__ bu_v, float* __restrict__ b1, float* __restrict__ b2) {
  int i = blockIdx.x * 256 + threadIdx.x;
  if (i < 512) b1[i] = bd_k[i];
  else if (i < 1024) b1[i] = bd_v[i - 512];
  else if (i < 3072) b1[i] = bq[i - 1024];
  else if (i < 5120) b2[i - 3072] = bu_k[i - 3072];
  else if (i < 7168) b2[i - 3072] = bu_v[i - 5120];
}

// ---------------------------------------------------------------------------
// 256x128x64 bf16 GEMM block, 4 waves (2Mx2N), per-wave 128x64, 16x16x32 MFMA.
// MULTI-DOMAIN design: single-buffered 48KB LDS -> 2 blocks/CU (two
// independent barrier domains). While one block drains vmcnt(0), the other's
// MFMAs run (m114 co-scheduling) - latency hiding across blocks, not within.
// Loop: stage(T) -> vmcnt(0) -> barrier -> compute -> barrier. setprio(1)
// around MFMA wins CU arbitration vs the co-resident block's staging.
// XOR-swizzled LDS via pre-swizzled global source (conflict-free, verified).
template <int OUT_BF16>
__global__ __launch_bounds__(256, 2) void gemm_bt(
    const unsigned short* __restrict__ A, int lda, int nsplit_col, int acol_off,
    const unsigned short* __restrict__ Bt, int ldb,
    const float* __restrict__ bias, void* __restrict__ Cp, int ldc,
    int K, int ntn) {
  __shared__ unsigned short Als[256 * 64];  // 32KB
  __shared__ unsigned short Bls[128 * 64];  // 16KB
  const int t = threadIdx.x;
  const int lane = t & 63, wave = t >> 6;

  // bijective XCD swizzle; bm-major => m-tile -> XCD = (m/8)&7, consistent
  // across GEMM1/2/3 (qx/ntn == 8 for all three grids).
  const int qx = gridDim.x >> 3;
  const int bid = (blockIdx.x & 7) * qx + (blockIdx.x >> 3);
  const int bm = (bid / ntn) * 256;
  const int bn = (bid % ntn) * 128;
  const unsigned short* Ab = A + (bn >= nsplit_col ? acol_off : 0);

  const int wr = wave >> 1, wc = wave & 1;
  const int g = lane >> 4, r = lane & 15;
  const int swz = r & 7;
  const int NT = K >> 6;

  f32x4 acc[8][4];
#pragma unroll
  for (int i = 0; i < 8; ++i)
#pragma unroll
    for (int j = 0; j < 4; ++j) acc[i][j] = (f32x4){0.f, 0.f, 0.f, 0.f};

  // staging: one issue = 32 rows x 64 cols (256 thr x 16B); thread t ->
  // row t>>3, source chunk inverse-XOR-swizzled (linear LDS dest).
  const int srow = t >> 3;
  const int jsrc = (t & 7) ^ (srow & 7);
  const unsigned short* aptr = Ab + (size_t)(bm + srow) * lda + (jsrc << 3);
  const unsigned short* bptr = Bt + (size_t)(bn + srow) * ldb + (jsrc << 3);
  const int wbase = wave * 512;  // wave-uniform LDS dest base (elems)

  for (int T = 0; T < NT; ++T) {
    const unsigned short* ak = aptr + (size_t)T * 64;
    const unsigned short* bk = bptr + (size_t)T * 64;
#pragma unroll
    for (int u = 0; u < 8; ++u)
      __builtin_amdgcn_global_load_lds(GLOBAL_AS(ak + (size_t)(u * 32) * lda),
                                       LDS_AS(&Als[u * 2048 + wbase]), 16, 0, 0);
#pragma unroll
    for (int u = 0; u < 4; ++u)
      __builtin_amdgcn_global_load_lds(GLOBAL_AS(bk + (size_t)(u * 32) * ldb),
                                       LDS_AS(&Bls[u * 2048 + wbase]), 16, 0, 0);
    WAITV(0);
    BARRIER();
#pragma unroll
    for (int ks = 0; ks < 2; ++ks) {
      const int c16 = (((ks << 2) + g) ^ swz) << 3;
      short8v bf[4];
#pragma unroll
      for (int ni = 0; ni < 4; ++ni)
        bf[ni] = *(const short8v*)&Bls[(wc * 64 + ni * 16 + r) * 64 + c16];
      __builtin_amdgcn_s_setprio(1);
#pragma unroll
      for (int mi = 0; mi < 8; ++mi) {
        short8v af = *(const short8v*)&Als[(wr * 128 + mi * 16 + r) * 64 + c16];
#pragma unroll
        for (int ni = 0; ni < 4; ++ni)
          acc[mi][ni] = __builtin_amdgcn_mfma_f32_16x16x32_bf16(
              af, bf[ni], acc[mi][ni], 0, 0, 0);
      }
      __builtin_amdgcn_s_setprio(0);
    }
    BARRIER();  // all reads done before next tile's stage overwrites
  }

#pragma unroll
  for (int ni = 0; ni < 4; ++ni) {
    const int col = bn + wc * 64 + ni * 16 + r;
    const float bv = bias[col];
#pragma unroll
    for (int mi = 0; mi < 8; ++mi) {
      const int row0 = bm + wr * 128 + mi * 16 + (g << 2);
#pragma unroll
      for (int j = 0; j < 4; ++j) {
        float v = acc[mi][ni][j] + bv;
        if (OUT_BF16)
          ((unsigned short*)Cp)[(size_t)(row0 + j) * ldc + col] = f2bf(v);
        else
          ((float*)Cp)[(size_t)(row0 + j) * ldc + col] = v;
      }
    }
  }
}

// ---------------------------------------------------------------------------
// Per-token head-vs-head attention (16x16 per token), fp32 math.
// Block o -> token (o&7)*2048 + (o>>3): same XCD as the GEMM blocks that
// wrote/will read this token's rows (m-tile -> XCD = (m/8)&7).
__global__ __launch_bounds__(256) void attn_kernel(
    const unsigned short* __restrict__ out1, const unsigned short* __restrict__ kv,
    unsigned short* __restrict__ aout) {
  const int o = blockIdx.x;
  const int s = (o & 7) * 2048 + (o >> 3);
  const int t = threadIdx.x;
  __shared__ float qs[16 * 132], ks2[16 * 132], vs[16 * 132];
  __shared__ float attn[256];
  const int h = t >> 4, d0 = (t & 15) * 8;

  union U8 { uint4v v; unsigned short us[8]; };
  U8 qv, kv8, vv;
  qv.v = *(const uint4v*)(out1 + (size_t)s * 3072 + 1024 + t * 8);
  kv8.v = *(const uint4v*)(kv + (size_t)s * 4096 + t * 8);
  vv.v = *(const uint4v*)(kv + (size_t)s * 4096 + 2048 + t * 8);
#pragma unroll
  for (int j = 0; j < 8; ++j) {
    qs[h * 132 + d0 + j] = bf2f(qv.us[j]);
    ks2[h * 132 + d0 + j] = bf2f(kv8.us[j]);
    vs[h * 132 + d0 + j] = bf2f(vv.us[j]);
  }
  __syncthreads();

  const int gg0 = t & 15;
  const f32x4* qrow = (const f32x4*)&qs[h * 132];
  const f32x4* krow = (const f32x4*)&ks2[gg0 * 132];
  float acc = 0.f;
#pragma unroll
  for (int dd = 0; dd < 32; ++dd) {
    f32x4 a4 = qrow[dd], b4 = krow[dd];
    acc += a4.x * b4.x + a4.y * b4.y + a4.z * b4.z + a4.w * b4.w;
  }
  acc *= 0.08838834764831845f;
  float mx = acc;
#pragma unroll
  for (int ofs = 8; ofs; ofs >>= 1) mx = fmaxf(mx, __shfl_xor(mx, ofs));
  float e = __expf(acc - mx);
  float sm = e;
#pragma unroll
  for (int ofs = 8; ofs; ofs >>= 1) sm += __shfl_xor(sm, ofs);
  attn[t] = e / sm;
  __syncthreads();

  f32x4 o0 = (f32x4){0.f, 0.f, 0.f, 0.f}, o1 = (f32x4){0.f, 0.f, 0.f, 0.f};
#pragma unroll
  for (int gg = 0; gg < 16; ++gg) {
    const float a = attn[(h << 4) + gg];
    f32x4 v0 = *(const f32x4*)&vs[gg * 132 + d0];
    f32x4 v1 = *(const f32x4*)&vs[gg * 132 + d0 + 4];
    o0 += v0 * a;
    o1 += v1 * a;
  }
  U8 ov;
  ov.us[0] = f2bf(o0.x); ov.us[1] = f2bf(o0.y); ov.us[2] = f2bf(o0.z); ov.us[3] = f2bf(o0.w);
  ov.us[4] = f2bf(o1.x); ov.us[5] = f2bf(o1.y); ov.us[6] = f2bf(o1.z); ov.us[7] = f2bf(o1.w);
  *(uint4v*)(aout + (size_t)s * 2048 + t * 8) = ov.v;
}

// ---------------------------------------------------------------------------
extern "C" void kernel_launch(void* const* d_in, const int* in_sizes, int n_in,
                              void* d_out, int out_size, void* d_ws, size_t ws_size,
                              hipStream_t stream) {
  (void)in_sizes; (void)n_in; (void)out_size; (void)ws_size;
  const float* x    = (const float*)d_in[0];
  const float* Wd_k = (const float*)d_in[1];
  const float* bd_k = (const float*)d_in[2];
  const float* Wu_k = (const float*)d_in[3];
  const float* bu_k = (const float*)d_in[4];
  const float* Wd_v = (const float*)d_in[5];
  const float* bd_v = (const float*)d_in[6];
  const float* Wu_v = (const float*)d_in[7];
  const float* bu_v = (const float*)d_in[8];
  const float* Wq   = (const float*)d_in[9];
  const float* bq   = (const float*)d_in[10];
  const float* Wo   = (const float*)d_in[11];
  const float* bo   = (const float*)d_in[12];

  char* ws = (char*)d_ws;
  unsigned short* w1t  = (unsigned short*)(ws);             // [3072][2048] bf16
  unsigned short* w2t  = (unsigned short*)(ws + 12582912);  // [4096][512]  bf16
  unsigned short* w3t  = (unsigned short*)(ws + 16777216);  // [2048][2048] bf16
  float*          b1   = (float*)(ws + 25165824);           // [3072]
  float*          b2   = (float*)(ws + 25178112);           // [4096]
  unsigned short* xb   = (unsigned short*)(ws + 25194496);  // [16384][2048] bf16
  unsigned short* out1 = (unsigned short*)(ws + 92303360);  // [16384][3072] bf16
  unsigned short* kvb  = (unsigned short*)(ws + 192966656); // [16384][4096] bf16
  unsigned short* attO = xb;  // reuse xb after GEMM1

  dim3 blk(256);

  transpose_to_bf16<<<dim3(16 * 64), blk, 0, stream>>>(Wd_k, w1t,               2048, 512, 16);
  transpose_to_bf16<<<dim3(16 * 64), blk, 0, stream>>>(Wd_v, w1t + 512 * 2048,  2048, 512, 16);
  transpose_to_bf16<<<dim3(64 * 64), blk, 0, stream>>>(Wq,   w1t + 1024 * 2048, 2048, 2048, 64);
  transpose_to_bf16<<<dim3(64 * 16), blk, 0, stream>>>(Wu_k, w2t,               512, 2048, 64);
  transpose_to_bf16<<<dim3(64 * 16), blk, 0, stream>>>(Wu_v, w2t + 2048 * 512,  512, 2048, 64);
  transpose_to_bf16<<<dim3(64 * 64), blk, 0, stream>>>(Wo,   w3t,               2048, 2048, 64);

  fill_bias<<<dim3(28), blk, 0, stream>>>(bd_k, bd_v, bq, bu_k, bu_v, b1, b2);

  cvt_f32_bf16<<<dim3(16384), blk, 0, stream>>>(x, xb);

  // GEMM1: [16384,2048]@[2048,3072] -> out1 (cache_k|cache_v|q); 64x24 tiles
  gemm_bt<1><<<dim3(64 * 24), blk, 0, stream>>>(
      xb, 2048, 1 << 30, 0, w1t, 2048, b1, out1, 3072, 2048, 24);

  // GEMM2 fused: k|v = [cache_k|cache_v]@blockdiag(Wu_k,Wu_v) -> kvb; 64x32
  gemm_bt<1><<<dim3(64 * 32), blk, 0, stream>>>(
      out1, 3072, 2048, 512, w2t, 512, b2, kvb, 4096, 512, 32);

  // per-token attention (XCD-aligned token order)
  attn_kernel<<<dim3(16384), blk, 0, stream>>>(out1, kvb, attO);

  // GEMM3: attO@Wo + bo -> d_out fp32; 64x16
  gemm_bt<0><<<dim3(64 * 16), blk, 0, stream>>>(
      attO, 2048, 1 << 30, 0, w3t, 2048, bo, (float*)d_out, 2048, 2048, 16);
}